// Round 11
// baseline (1311.489 us; speedup 1.0000x reference)
//
#include <hip/hip_runtime.h>
#include <math.h>

// ---------------- types ----------------
typedef _Float16 f16;
typedef _Float16 f16x8 __attribute__((ext_vector_type(8)));
typedef float f32x4 __attribute__((ext_vector_type(4)));

#define DEV static __device__ __forceinline__

DEV float sigm(float x)  { return 1.0f / (1.0f + __expf(-x)); }
DEV float tanhfast(float x) { return 2.0f / (1.0f + __expf(-2.0f * x)) - 1.0f; }

// async global->LDS, 16B per lane (dest must be wave-uniform base + lane*16)
DEV void gld16(const void* g, void* l) {
  __builtin_amdgcn_global_load_lds((const __attribute__((address_space(1))) void*)g,
                                   (__attribute__((address_space(3))) void*)l, 16, 0, 0);
}

// minimal-fence group barrier (R9/R10-proven): release rides the arrival RMW,
// spin is RELAXED (no per-poll L2 inv), single ACQUIRE load on exit.
DEV void gbar(int* bar, int nblk) {
  __syncthreads();
  if (threadIdx.x == 0) {
    int* cnt = bar;
    int* gen = bar + 16;
    int g = __hip_atomic_load(gen, __ATOMIC_RELAXED, __HIP_MEMORY_SCOPE_AGENT);
    int a = __hip_atomic_fetch_add(cnt, 1, __ATOMIC_RELEASE, __HIP_MEMORY_SCOPE_AGENT);
    if (a == nblk - 1) {
      __hip_atomic_store(cnt, 0, __ATOMIC_RELAXED, __HIP_MEMORY_SCOPE_AGENT);
      __hip_atomic_store(gen, g + 1, __ATOMIC_RELEASE, __HIP_MEMORY_SCOPE_AGENT);
    } else {
      while (__hip_atomic_load(gen, __ATOMIC_RELAXED, __HIP_MEMORY_SCOPE_AGENT) == g)
        __builtin_amdgcn_s_sleep(1);
    }
    (void)__hip_atomic_load(gen, __ATOMIC_ACQUIRE, __HIP_MEMORY_SCOPE_AGENT); // single inv
  }
  __syncthreads();
}

// ---------------- problem constants ----------------
// B=256 V=50 N=32 D=128 H=384 L=12 CS=10 ND=4096 G=1560 OUT=128
#define GP 1664   // padded G (13*128) — XK gemm N and XKh row stride
#define KH 3840   // H*CS (conv gemm K)
#define KO 19200  // V*H  (out gemm K)
// recurrence: 16 groups (16 batches each) x 12 members (member m owns gate-group l=m)
#define NGRP 16
#define NMEM 12
#define NBLK 192
#define XOLS 164  // xo local (LDS) row stride in f32
// dyn LDS: Wl 10 tiles x 12288 B + xol 16x164 f32
#define RECUR_LDS (122880 + 10496)   // 133376

// ---------------- workspace layout (bytes) ----------------
static constexpr size_t OFF_X     = 0;                       // xf 104857600; lh/opart alias later
static constexpr size_t OFF_LH    = 0;
static constexpr size_t OFF_OPART = 0;                       // out partials 8*32768*4
static constexpr size_t OFF_ZB    = 1048576;                 // zero h buffer f16 256*384*2 = 196608 (xf alias)
static constexpr size_t OFF_WK    = 104857600;               // 13631488
static constexpr size_t OFF_XK    = OFF_WK + 13631488;       // XKh f16 12800*1664*2 = 42598400
// aliases of the XK region (XKh dead after k_recur):
static constexpr size_t OFF_MLH   = OFF_XK;                  // mlh_h f16 9830400
static constexpr size_t OFF_S1    = OFF_XK + 9830400;        // s1h f16 3276800
static constexpr size_t OFF_TH    = OFF_XK + 13107200;       // theme f32 19660800
static constexpr size_t OFF_CV    = OFF_XK + 32768000;       // conv partials 2x19660800 (ends +72089600)
static constexpr size_t OFF_SWP   = OFF_XK + 72089600;       // swp f16 98304 (> XKh end)
static constexpr size_t OFF_RWP2  = OFF_XK + 72187904;       // rwp2 f16 98304
static constexpr size_t OFF_SBP   = OFF_XK + 72286208;       // sbp f32 512
static constexpr size_t OFF_RW    = OFF_XK + 85196800;       // RWpack f16 12*10*12288 = 1474560
static constexpr size_t OFF_SV    = OFF_RW + 1474560;        // Sv f32 6656 (pad 8192)
static constexpr size_t OFF_BAR   = OFF_SV + 8192;           // barrier state 16 groups x 32 ints = 8192
static constexpr size_t OFF_BIASC = OFF_BAR + 8192;          // 8192
static constexpr size_t OFF_HALL  = OFF_BIASC + 8192;        // h_all f16 50*256*384*2 = 9830400
static constexpr size_t OFF_LD    = OFF_HALL + 9830400;      // 512000
static constexpr size_t OFF_WC2   = OFF_LD + 512000;         // 2949120
static constexpr size_t OFF_RNN   = OFF_WC2 + 2949120;       // 9830400
static constexpr size_t OFF_OUTW  = OFF_RNN + 9830400;       // 4915200

// ---------------- kernels ----------------

// embedding gather -> x_f16 (12800 x 4096), 8 halfs / thread
__global__ __launch_bounds__(256) void k_gather(const int* __restrict__ ids,
                                                const float* __restrict__ embed,
                                                f16* __restrict__ xf) {
  int i = blockIdx.x * 256 + threadIdx.x;     // 12800*512 total
  int row = i >> 9;
  int c8  = i & 511;
  int n = c8 >> 4;
  int d = (c8 & 15) << 3;
  int id = ids[row * 32 + n];
  const float* e = embed + (long)id * 128 + d;
  float4 a = *(const float4*)e;
  float4 b = *(const float4*)(e + 4);
  f16x8 o;
  o[0]=(f16)a.x; o[1]=(f16)a.y; o[2]=(f16)a.z; o[3]=(f16)a.w;
  o[4]=(f16)b.x; o[5]=(f16)b.y; o[6]=(f16)b.z; o[7]=(f16)b.w;
  *(f16x8*)(xf + ((long)row << 12) + (c8 << 3)) = o;
}

// kernel_w (1560 x 4097) -> Wk_f16 (1664 x 4096, zero-padded rows); biasc = kb+rb (padded 1664)
__global__ __launch_bounds__(256) void k_prep_wk(const float* __restrict__ kw,
                                                 const float* __restrict__ kb,
                                                 const float* __restrict__ rb,
                                                 f16* __restrict__ Wk,
                                                 float* __restrict__ biasc) {
  long i = (long)blockIdx.x * 256 + threadIdx.x;
  if (i < 1664L * 4096) {
    int nn = (int)(i >> 12);
    int k  = (int)(i & 4095);
    float v = (nn < 1560) ? kw[(long)nn * 4097 + k] : 0.0f;
    Wk[i] = (f16)v;
  }
  if (i < 1664) biasc[i] = (i < 1560) ? (kb[i] + rb[i]) : 0.0f;
}

// rec_w (1560x385) -> member-packed RWp: RWp[m][tile τ<10][f<12][lane<64][e<8].
// Member m local col lc = τ*16+(lane&15): lc<24 -> orig col lc (fm/im logits,
// replicated); 24<=lc<32 -> zero pad; lc>=32 -> run=(lc-32)/32 (f,i,o,cin),
// orig col = 24 + (run*12+m)*32 + (lc-32)%32.  k = f*32 + (lane>>4)*8 + e.
__global__ __launch_bounds__(512) void k_prep_rwpack(const float* __restrict__ rw,
                                                     const float* __restrict__ kw,
                                                     f16* __restrict__ RWp,
                                                     float* __restrict__ Sv,
                                                     int* __restrict__ bar) {
  int i = blockIdx.x * 512 + threadIdx.x;      // 12*10*12*64 = 92160 chunks of 8 halfs
  if (i < 92160) {
    int p = i / 7680;
    int rem = i - p * 7680;
    int tau = rem / 768;
    int r2 = rem - tau * 768;
    int f = r2 >> 6;
    int l = r2 & 63;
    int lc = tau * 16 + (l & 15);
    int n;
    if (lc < 24) n = lc;
    else if (lc < 32) n = -1;
    else { int run = (lc - 32) >> 5; n = 24 + (run * 12 + p) * 32 + ((lc - 32) & 31); }
    int k = f * 32 + ((l >> 4) << 3);
    f16x8 o;
    if (n >= 0) {
      const float* s = rw + (long)n * 385 + k;
#pragma unroll
      for (int e = 0; e < 8; ++e) o[e] = (f16)s[e];
    } else {
#pragma unroll
      for (int e = 0; e < 8; ++e) o[e] = (f16)0.0f;
    }
    *(f16x8*)(RWp + (long)i * 8) = o;
  }
  if (i < 1664)
    Sv[i] = (i < 1560) ? (rw[(long)i * 385 + 384] + kw[(long)i * 4097 + 4096]) : 0.0f;
  if (i < 2048) bar[i] = 0;
}

// conv_w (384,384,10) -> Wc2_f16[o][j*384+h]
__global__ __launch_bounds__(256) void k_prep_wc(const float* __restrict__ cw,
                                                 f16* __restrict__ Wc2) {
  int i = blockIdx.x * 256 + threadIdx.x;     // 384*3840
  if (i >= 384 * 3840) return;
  int o = i / 3840;
  int c = i - o * 3840;
  int j = c / 384;
  int h = c - j * 384;
  Wc2[i] = (f16)cw[((long)o * 384 + h) * 10 + j];
}

// scale_w (64,384)->swp(128,384,f16,zero-pad rows); scale_b->sbp(128); rescale_w(384,64)->rwp2(384,128,zero-pad cols)
__global__ __launch_bounds__(256) void k_prep_scale(const float* __restrict__ sw,
                                                    const float* __restrict__ sb,
                                                    const float* __restrict__ rw2,
                                                    f16* __restrict__ swp,
                                                    float* __restrict__ sbp,
                                                    f16* __restrict__ rwp2) {
  int i = blockIdx.x * 256 + threadIdx.x;   // 49152
  if (i < 128 * 384) {
    int o = i / 384, k = i - o * 384;
    swp[i] = (f16)((o < 64) ? sw[o * 384 + k] : 0.0f);
    int o2 = i >> 7, k2 = i & 127;
    rwp2[i] = (f16)((k2 < 64) ? rw2[o2 * 64 + k2] : 0.0f);
  }
  if (i < 128) sbp[i] = (i < 64) ? sb[i] : 0.0f;
}

// generic fp32 -> f16 convert
__global__ __launch_bounds__(256) void k_cvt(const float* __restrict__ src,
                                             f16* __restrict__ dst, long n) {
  long i = (long)blockIdx.x * 256 + threadIdx.x;
  if (i < n) dst[i] = (f16)src[i];
}

// C = A(M x K) * W(N x K)^T (+bias[col]); m97-style global_load_lds staging.
// grid.z splits K (kLen MUST be a multiple of 32; partials at z*M*N).
// act: 0=f32, 1=f16, 2=relu->f16, 3=sigmoid->f32.
__global__ __launch_bounds__(256) void k_gemm_bt(const f16* __restrict__ A,
                                                 const f16* __restrict__ W,
                                                 void* __restrict__ Cv,
                                                 const float* __restrict__ bias,
                                                 int N, int K, int kLen, int act) {
  __shared__ __align__(16) f16 As[128 * 32];   // unpadded: global_load_lds needs lane-contiguous dest
  __shared__ __align__(16) f16 Bs[128 * 32];
  const int tid = threadIdx.x;
  const long rowA0 = (long)blockIdx.x * 128;
  const long rowB0 = (long)blockIdx.y * 128;
  const long ks = (long)blockIdx.z * kLen;
  const long zoff = (long)blockIdx.z * ((long)gridDim.x * 128 * N);
  const int w = tid >> 6, lane = tid & 63;
  const int q = lane >> 4, r16 = lane & 15;
  const int wr = w >> 1, wc = w & 1;
  f32x4 acc[4][4] = {};
  const int srow = tid >> 2;
  const int scol = (tid & 3) * 8;
  const f16* gA0 = A + (rowA0 + srow) * (long)K + ks + scol;
  const f16* gA1 = gA0 + 64L * K;
  const f16* gB0 = W + (rowB0 + srow) * (long)K + ks + scol;
  const f16* gB1 = gB0 + 64L * K;
  f16* lA = As + tid * 8;
  f16* lB = Bs + tid * 8;
  for (int k0 = 0; k0 < kLen; k0 += 32) {
    __syncthreads();
    gld16(gA0 + k0, lA);
    gld16(gA1 + k0, lA + 2048);
    gld16(gB0 + k0, lB);
    gld16(gB1 + k0, lB + 2048);
    __syncthreads();
    f16x8 af[4], bfr[4];
#pragma unroll
    for (int i = 0; i < 4; i++) {
      af[i]  = *(const f16x8*)&As[(wr * 64 + i * 16 + r16) * 32 + q * 8];
      bfr[i] = *(const f16x8*)&Bs[(wc * 64 + i * 16 + r16) * 32 + q * 8];
    }
#pragma unroll
    for (int i = 0; i < 4; i++)
#pragma unroll
      for (int j = 0; j < 4; j++)
        acc[i][j] = __builtin_amdgcn_mfma_f32_16x16x32_f16(af[i], bfr[j], acc[i][j], 0, 0, 0);
  }
#pragma unroll
  for (int i = 0; i < 4; i++)
#pragma unroll
    for (int j = 0; j < 4; j++) {
      long row = rowA0 + wr * 64 + i * 16 + q * 4;
      long col = rowB0 + wc * 64 + j * 16 + r16;
      float bv = bias ? bias[col] : 0.0f;
#pragma unroll
      for (int r = 0; r < 4; r++) {
        float v = acc[i][j][r] + bv;
        long off = (row + r) * (long)N + col + zoff;
        if (act == 0)      ((float*)Cv)[off] = v;
        else if (act == 1) ((f16*)Cv)[off]   = (f16)v;
        else if (act == 2) ((f16*)Cv)[off]   = (f16)fmaxf(v, 0.0f);
        else               ((float*)Cv)[off] = sigm(v);
      }
    }
}

// gate-partitioned weights-stationary recurrence v2: 192 blocks = 16 groups x 12
// members, 640 threads (10 waves). Group owns 16 batches; member m owns gate-group
// l=m; wave w (<10) owns packed N-tile w (weights stationary in LDS). xo is
// block-local LDS. Cross-step XKh register prefetch (t+1 loaded during t).
// ONE group barrier per step (h(t) publication).
__global__ __launch_bounds__(640)
void k_recur_coop(const f16* __restrict__ XKh,    // (12800,1664) f16, bias folded
                  const f16* __restrict__ RWp,    // member-packed (12,10,12,64,8) f16
                  const float* __restrict__ Sv,   // (1664)
                  const float* __restrict__ timep,// (256,50)
                  f16* __restrict__ zbuf,         // (256,384) zeroed here
                  f16* __restrict__ hall,         // (50,256,384) f16
                  float* __restrict__ dists,      // (50,256)
                  int* __restrict__ bar) {
  extern __shared__ char smem[];
  f16*   Wl  = (f16*)smem;                        // 10 tiles x 6144 halfs
  float* xol = (float*)(smem + 122880);           // 16 x XOLS
  const int tid = threadIdx.x;
  const int g = blockIdx.x / NMEM;
  const int m = blockIdx.x - g * NMEM;            // this member's l
  const int b0 = g * 16;
  int* gbbar = bar + 32 * g;
  const int w = tid >> 6, lane = tid & 63;
  const int q = lane >> 4, r16 = lane & 15;
  // stationary member weights -> LDS (once)
  {
    const f16* src = RWp + (size_t)m * 61440;
    for (int i = tid; i < 7680; i += 640)
      *(f16x8*)(Wl + (size_t)i * 8) = *(const f16x8*)(src + (size_t)i * 8);
  }
  // per-lane column meta (loop-invariant): wave w owns tile w
  int ncol = -1; float Svc = 0.0f;
  if (w < 10) {
    const int lc = w * 16 + r16;
    if (lc < 24) ncol = lc;
    else if (lc >= 32) { int run = (lc - 32) >> 5; ncol = 24 + (run * 12 + m) * 32 + ((lc - 32) & 31); }
    if (ncol >= 0) Svc = Sv[ncol];
  }
  // zero the group's 16 zbuf rows (16*384/8 = 768 chunks, split across members)
  {
    f16x8 z = {};
    for (int i = m * 640 + tid; i < 768; i += NMEM * 640)
      *(f16x8*)(zbuf + (size_t)b0 * 384 + (size_t)i * 8) = z;
  }
  gbar(gbbar, NMEM);

  const int ch = tid & 31, bloc = tid >> 5;       // gates: bloc < 16 -> batch
  float creg = 0.0f;
  // preload xk for t=0
  f16 xkc[4] = {};
  if (w < 10 && ncol >= 0) {
#pragma unroll
    for (int r = 0; r < 4; ++r)
      xkc[r] = XKh[((long)(b0 + q * 4 + r) * 50) * GP + ncol];
  }

  for (int t = 0; t < 50; ++t) {
    const f16* hprev = (t == 0) ? zbuf : (hall + (size_t)(t - 1) * 98304);
    f16 xkn[4] = {};
    if (w < 10) {
      // issue next-step XKh first: a full step of slack to land
      if (t < 49 && ncol >= 0) {
#pragma unroll
        for (int r = 0; r < 4; ++r)
          xkn[r] = XKh[((long)(b0 + q * 4 + r) * 50 + (t + 1)) * GP + ncol];
      }
      float tv4[4];
#pragma unroll
      for (int r = 0; r < 4; ++r) tv4[r] = timep[(b0 + q * 4 + r) * 50 + t];
      f16x8 af[12];
      const f16* ab = hprev + (size_t)(b0 + r16) * 384 + q * 8;
#pragma unroll
      for (int f = 0; f < 12; ++f) af[f] = *(const f16x8*)(ab + f * 32);
      const f16* bp = Wl + (size_t)w * 6144 + lane * 8;
      f32x4 a0 = {};
#pragma unroll
      for (int f = 0; f < 12; ++f)
        a0 = __builtin_amdgcn_mfma_f32_16x16x32_f16(af[f], *(const f16x8*)(bp + f * 512), a0, 0, 0, 0);
      const int lc = w * 16 + r16;
#pragma unroll
      for (int r = 0; r < 4; ++r)
        xol[(q * 4 + r) * XOLS + lc] = a0[r] + (float)xkc[r] + tv4[r] * Svc;
    }
    __syncthreads();   // xol ready (block-local)
    // ---- gates for l=m: thread (batch bloc, channel ch), bloc < 16 ----
    if (bloc < 16) {
      const int gb = b0 + bloc;
      const float* xr = xol + bloc * XOLS;
      float e1[12], e2[12], mx1 = -1e30f, mx2 = -1e30f;
#pragma unroll
      for (int l = 0; l < 12; ++l) {
        e1[l] = xr[l];      mx1 = fmaxf(mx1, e1[l]);
        e2[l] = xr[12 + l]; mx2 = fmaxf(mx2, e2[l]);
      }
      float s1 = 0.0f, s2 = 0.0f;
#pragma unroll
      for (int l = 0; l < 12; ++l) {
        e1[l] = __expf(e1[l] - mx1); s1 += e1[l];
        e2[l] = __expf(e2[l] - mx2); s2 += e2[l];
      }
      float cum1 = 0.0f;
      for (int l = 0; l <= m; ++l) cum1 += e1[l];
      const float fmv = cum1 / s1;
      float cum2 = 0.0f;
      for (int l = 11; l >= m; --l) cum2 += e2[l];
      const float imv = cum2 / s2;
      if (m == 0 && ch == 0) {
        float ds = 0.0f;
#pragma unroll
        for (int l = 0; l < 12; ++l) ds += (float)(12 - l) * e1[l];
        dists[t * 256 + gb] = 1.0f - ds / (12.0f * s1);
      }
      const float fv = sigm(xr[32 + ch]);
      const float iv = sigm(xr[64 + ch]);
      const float og = sigm(xr[96 + ch]);
      const float ci = tanhfast(xr[128 + ch]);
      const float ov = fmv * imv;
      const float cn = ov * (fv * creg + iv * ci) + (fmv - ov) * creg + (imv - ov) * ci;
      creg = cn;
      const float hv = og * tanhfast(cn);
      hall[((size_t)t * 256 + gb) * 384 + m * 32 + ch] = (f16)hv;
    }
    gbar(gbbar, NMEM);   // h(t) visible group-wide for GEMM(t+1); guards xol reuse
#pragma unroll
    for (int r = 0; r < 4; ++r) xkc[r] = xkn[r];
  }
}

// ld[b,t,:] = softmax_j(cumsum_j dist[t-9+j])
__global__ __launch_bounds__(256) void k_ld(const float* __restrict__ dists,
                                            float* __restrict__ ld) {
  int i = blockIdx.x * 256 + threadIdx.x;
  if (i >= 12800) return;
  int b = i / 50, t = i - b * 50;
  float v[10];
  float cum = 0.0f, mx = -1e30f;
#pragma unroll
  for (int j = 0; j < 10; j++) {
    int s = t - 9 + j;
    float d = (s >= 0) ? dists[s * 256 + b] : 0.0f;
    cum += d; v[j] = cum; mx = fmaxf(mx, cum);
  }
  float sum = 0.0f;
#pragma unroll
  for (int j = 0; j < 10; j++) { v[j] = __expf(v[j] - mx); sum += v[j]; }
  float inv = 1.0f / sum;
#pragma unroll
  for (int j = 0; j < 10; j++) ld[i * 10 + j] = v[j] * inv;
}

// lh_f16[(b,t)][j*384+h] = ld[b,t,j] * h_{t-9+j}[b,h]   (h_all is f16)
__global__ __launch_bounds__(256) void k_lh(const float* __restrict__ ld,
                                            const f16* __restrict__ h_all,
                                            f16* __restrict__ lh) {
  int i = blockIdx.x * 256 + threadIdx.x;   // 12800*480
  int row = i / 480;
  int c = i - row * 480;
  int j = c / 48;
  int h0 = (c - j * 48) * 8;
  int b = row / 50, t = row - b * 50;
  int s = t - 9 + j;
  f16x8 o;
  if (s >= 0) {
    float wv = ld[row * 10 + j];
    f16x8 hv8 = *(const f16x8*)(h_all + ((size_t)s * 256 + b) * 384 + h0);
#pragma unroll
    for (int k = 0; k < 8; k++) o[k] = (f16)(wv * (float)hv8[k]);
  } else {
#pragma unroll
    for (int k = 0; k < 8; k++) o[k] = (f16)0.0f;
  }
  *(f16x8*)(lh + (long)row * KH + j * 384 + h0) = o;
}

// mlh_h[(b,t)][h] = mean_j
__global__ __launch_bounds__(256) void k_mlh(const float* __restrict__ ld,
                                             const f16* __restrict__ h_all,
                                             f16* __restrict__ mlh) {
  int i = blockIdx.x * 256 + threadIdx.x;   // 12800*384
  int row = i / 384, h = i - row * 384;
  int b = row / 50, t = row - b * 50;
  float acc = 0.0f;
#pragma unroll
  for (int j = 0; j < 10; j++) {
    int s = t - 9 + j;
    if (s >= 0) acc += ld[row * 10 + j] * (float)h_all[((size_t)s * 256 + b) * 384 + h];
  }
  mlh[i] = (f16)(acc * 0.1f);
}

// rnn_f16[b][t*384+h] = theme*(conv0+conv1+conv_b) + h
__global__ __launch_bounds__(256) void k_rnn(const float* __restrict__ theme,
                                             const float* __restrict__ convp,  // 2 partials
                                             const float* __restrict__ cb,
                                             const f16* __restrict__ h_all,
                                             f16* __restrict__ rnn) {
  int i = blockIdx.x * 256 + threadIdx.x;   // 12800*384, ordered (b,t,h)
  int row = i / 384, h = i - row * 384;
  int b = row / 50, t = row - b * 50;
  float conv = convp[i] + convp[4915200 + i] + cb[h];
  float local = theme[i] * conv;
  float hv = (float)h_all[((size_t)t * 256 + b) * 384 + h];
  rnn[i] = (f16)(local + hv);               // (b*50+t)*384+h == b*19200 + t*384 + h
}

// out[i] = sum_z part[z][i] + out_b
__global__ __launch_bounds__(256) void k_red8(const float* __restrict__ part,
                                              const float* __restrict__ ob,
                                              float* __restrict__ out) {
  int i = blockIdx.x * 256 + threadIdx.x;   // 32768
  float s = 0.0f;
#pragma unroll
  for (int z = 0; z < 8; z++) s += part[z * 32768 + i];
  out[i] = s + ob[i & 127];
}

// ---------------- launch ----------------
extern "C" void kernel_launch(void* const* d_in, const int* in_sizes, int n_in,
                              void* d_out, int out_size, void* d_ws, size_t ws_size,
                              hipStream_t stream) {
  (void)in_sizes; (void)n_in; (void)out_size; (void)ws_size;
  const int*   node_ids  = (const int*)  d_in[0];
  const float* timep     = (const float*)d_in[3];
  const float* embed     = (const float*)d_in[6];
  const float* kernel_w  = (const float*)d_in[7];
  const float* kernel_b  = (const float*)d_in[8];
  const float* rec_w     = (const float*)d_in[9];
  const float* rec_b     = (const float*)d_in[10];
  const float* scale_w   = (const float*)d_in[11];
  const float* scale_b   = (const float*)d_in[12];
  const float* rescale_w = (const float*)d_in[13];
  const float* rescale_b = (const float*)d_in[14];
  const float* conv_w    = (const float*)d_in[15];
  const float* conv_b    = (const float*)d_in[16];
  const float* out_w     = (const float*)d_in[17];
  const float* out_b     = (const float*)d_in[18];

  char* ws = (char*)d_ws;
  f16*   xf      = (f16*)  (ws + OFF_X);
  f16*   lh      = (f16*)  (ws + OFF_LH);
  float* opart   = (float*)(ws + OFF_OPART);
  f16*   zbuf    = (f16*)  (ws + OFF_ZB);
  f16*   Wk      = (f16*)  (ws + OFF_WK);
  f16*   XKh     = (f16*)  (ws + OFF_XK);
  f16*   mlh_h   = (f16*)  (ws + OFF_MLH);
  f16*   s1h     = (f16*)  (ws + OFF_S1);
  float* theme   = (float*)(ws + OFF_TH);
  float* convbuf = (float*)(ws + OFF_CV);
  f16*   swp     = (f16*)  (ws + OFF_SWP);
  f16*   rwp2    = (f16*)  (ws + OFF_RWP2);
  float* sbp     = (float*)(ws + OFF_SBP);
  f16*   RWp     = (f16*)  (ws + OFF_RW);
  float* Sv      = (float*)(ws + OFF_SV);
  int*   bar     = (int*)  (ws + OFF_BAR);
  float* biasc   = (float*)(ws + OFF_BIASC);
  f16*   h_all   = (f16*)  (ws + OFF_HALL);
  float* ldbuf   = (float*)(ws + OFF_LD);
  f16*   Wc2     = (f16*)  (ws + OFF_WC2);
  f16*   rnn     = (f16*)  (ws + OFF_RNN);
  f16*   outw    = (f16*)  (ws + OFF_OUTW);

  float* outp  = (float*)d_out;          // (256,128)
  float* dists = outp + 256 * 128;       // (50,256)

  // phase 0: prep
  k_gather     <<<25600, 256, 0, stream>>>(node_ids, embed, xf);
  k_prep_wk    <<<26624, 256, 0, stream>>>(kernel_w, kernel_b, rec_b, Wk, biasc);
  k_prep_rwpack<<<180,   512, 0, stream>>>(rec_w, kernel_w, RWp, Sv, bar);
  k_prep_scale <<<192,   256, 0, stream>>>(scale_w, scale_b, rescale_w, swp, sbp, rwp2);
  k_prep_wc    <<<5760,  256, 0, stream>>>(conv_w, Wc2);
  // phase 1: XKh = f16( x @ kernel_w^T + (kernel_b + rec_b) )
  k_gemm_bt<<<dim3(100, 13), 256, 0, stream>>>(xf, Wk, XKh, biasc, GP, 4096, 4096, 1);
  // phase 2: gate-partitioned weights-stationary recurrence (1 barrier/step,
  // cross-step XKh prefetch, 16 groups x 12 members x 640 threads)
  {
    hipFuncSetAttribute((const void*)k_recur_coop,
                        hipFuncAttributeMaxDynamicSharedMemorySize, RECUR_LDS);
    void* cargs[] = {(void*)&XKh, (void*)&RWp, (void*)&Sv, (void*)&timep,
                     (void*)&zbuf, (void*)&h_all, (void*)&dists, (void*)&bar};
    hipLaunchCooperativeKernel((void*)k_recur_coop, dim3(NBLK), dim3(640),
                               cargs, RECUR_LDS, stream);
  }
  // phase 3: deferred outputs (fully parallel)
  k_ld  <<<50,    256, 0, stream>>>(dists, ldbuf);
  k_lh  <<<24000, 256, 0, stream>>>(ldbuf, h_all, lh);
  k_mlh <<<19200, 256, 0, stream>>>(ldbuf, h_all, mlh_h);
  k_gemm_bt<<<dim3(100, 1), 256, 0, stream>>>(mlh_h, swp, s1h, sbp, 128, 384, 384, 2);
  k_gemm_bt<<<dim3(100, 3), 256, 0, stream>>>(s1h, rwp2, theme, rescale_b, 384, 128, 128, 3);
  k_gemm_bt<<<dim3(100, 3, 2), 256, 0, stream>>>(lh, Wc2, convbuf, nullptr, 384, KH, KH / 2, 0);
  k_rnn <<<19200, 256, 0, stream>>>(theme, convbuf, conv_b, h_all, rnn);
  k_cvt <<<9600,  256, 0, stream>>>(out_w, outw, 128L * KO);
  // phase 4: out = rnn @ out_w^T + out_b   (K split 8 ways: 2400 = 75*32, exact)
  k_gemm_bt<<<dim3(2, 1, 8), 256, 0, stream>>>(rnn, outw, opart, nullptr, 128, KO, KO / 8, 0);
  k_red8<<<128, 256, 0, stream>>>(opart, out_b, outp);
}

// Round 12
// 1118.104 us; speedup vs baseline: 1.1730x; 1.1730x over previous
//
#include <hip/hip_runtime.h>
#include <math.h>

// ---------------- types ----------------
typedef _Float16 f16;
typedef _Float16 f16x8 __attribute__((ext_vector_type(8)));
typedef float f32x4 __attribute__((ext_vector_type(4)));

#define DEV static __device__ __forceinline__

DEV float sigm(float x)  { return 1.0f / (1.0f + __expf(-x)); }
DEV float tanhfast(float x) { return 2.0f / (1.0f + __expf(-2.0f * x)) - 1.0f; }

// async global->LDS, 16B per lane (dest must be wave-uniform base + lane*16)
DEV void gld16(const void* g, void* l) {
  __builtin_amdgcn_global_load_lds((const __attribute__((address_space(1))) void*)g,
                                   (__attribute__((address_space(3))) void*)l, 16, 0, 0);
}

// LLC-coherent f16 store: sc0 sc1 bypasses L1/L2 so the value is visible
// device-wide without any wbl2/inv fence on the consumer side.
DEV void st_f16_llc(f16* p, f16 v) {
  unsigned int u = *(unsigned short*)&v;
  asm volatile("global_store_short %0, %1, off sc0 sc1" :: "v"(p), "v"(u) : "memory");
}

// init-only barrier (release/acquire) — used once before the t-loop
DEV void gbar(int* bar, int nblk) {
  __syncthreads();
  if (threadIdx.x == 0) {
    int* cnt = bar;
    int* gen = bar + 16;
    int g = __hip_atomic_load(gen, __ATOMIC_RELAXED, __HIP_MEMORY_SCOPE_AGENT);
    int a = __hip_atomic_fetch_add(cnt, 1, __ATOMIC_RELEASE, __HIP_MEMORY_SCOPE_AGENT);
    if (a == nblk - 1) {
      __hip_atomic_store(cnt, 0, __ATOMIC_RELAXED, __HIP_MEMORY_SCOPE_AGENT);
      __hip_atomic_store(gen, g + 1, __ATOMIC_RELEASE, __HIP_MEMORY_SCOPE_AGENT);
    } else {
      while (__hip_atomic_load(gen, __ATOMIC_RELAXED, __HIP_MEMORY_SCOPE_AGENT) == g)
        __builtin_amdgcn_s_sleep(1);
    }
    (void)__hip_atomic_load(gen, __ATOMIC_ACQUIRE, __HIP_MEMORY_SCOPE_AGENT);
  }
  __syncthreads();
}

// ---------------- problem constants ----------------
// B=256 V=50 N=32 D=128 H=384 L=12 CS=10 ND=4096 G=1560 OUT=128
#define GP 1664   // padded G (13*128) — XK gemm N and XKh row stride
#define KH 3840   // H*CS (conv gemm K)
#define KO 19200  // V*H  (out gemm K)
#define NGRP 16
#define NMEM 12
#define NBLK 192
#define XOLS 164  // xo local (LDS) row stride in f32
#define RECUR_LDS (122880 + 10496)   // Wl 10 tiles + xol 16x164 f32

// ---------------- workspace layout (bytes) ----------------
static constexpr size_t OFF_LH    = 0;                       // lh f16 98304000; opart aliases
static constexpr size_t OFF_OPART = 0;
static constexpr size_t OFF_ZB    = 104857600 - 262144;      // zbuf f16 196608 (tail of lh region, dead during recur)
static constexpr size_t OFF_WK    = 104857600;               // 13631488
static constexpr size_t OFF_XK    = OFF_WK + 13631488;       // XKh f16 42598400
// aliases of the XK region (XKh dead after k_recur):
static constexpr size_t OFF_MLH   = OFF_XK;                  // mlh_h f16 9830400
static constexpr size_t OFF_S1    = OFF_XK + 9830400;        // s1h f16 3276800
static constexpr size_t OFF_TH    = OFF_XK + 13107200;       // theme f32 19660800
static constexpr size_t OFF_CV    = OFF_XK + 32768000;       // conv partials 2x19660800 (ends +72089600)
static constexpr size_t OFF_SWP   = OFF_XK + 72089600;       // swp f16 98304 (> XKh end)
static constexpr size_t OFF_RWP2  = OFF_XK + 72187904;       // rwp2 f16 98304
static constexpr size_t OFF_SBP   = OFF_XK + 72286208;       // sbp f32 512
static constexpr size_t OFF_RW    = OFF_XK + 85196800;       // RWpack f16 1474560
static constexpr size_t OFF_SV    = OFF_RW + 1474560;        // Sv f32 6656 (pad 8192)
static constexpr size_t OFF_BAR   = OFF_SV + 8192;           // flags 16*256 ints + init gbar 16*32 ints (32 KB)
static constexpr size_t OFF_BIASC = OFF_BAR + 32768;         // 8192
static constexpr size_t OFF_HALL  = OFF_BIASC + 8192;        // h_all f16 9830400
static constexpr size_t OFF_LD    = OFF_HALL + 9830400;      // 512000
static constexpr size_t OFF_WC2   = OFF_LD + 512000;         // 2949120
static constexpr size_t OFF_RNN   = OFF_WC2 + 2949120;       // 9830400
static constexpr size_t OFF_OUTW  = OFF_RNN + 9830400;       // 4915200
static constexpr size_t OFF_EH    = OFF_OUTW + 4915200;      // embed f16 10001*128*2 = 2560256

// ---------------- kernels ----------------

// kernel_w (1560 x 4097) -> Wk_f16 (1664 x 4096, zero-padded rows); biasc = kb+rb (padded 1664)
__global__ __launch_bounds__(256) void k_prep_wk(const float* __restrict__ kw,
                                                 const float* __restrict__ kb,
                                                 const float* __restrict__ rb,
                                                 f16* __restrict__ Wk,
                                                 float* __restrict__ biasc) {
  long i = (long)blockIdx.x * 256 + threadIdx.x;
  if (i < 1664L * 4096) {
    int nn = (int)(i >> 12);
    int k  = (int)(i & 4095);
    float v = (nn < 1560) ? kw[(long)nn * 4097 + k] : 0.0f;
    Wk[i] = (f16)v;
  }
  if (i < 1664) biasc[i] = (i < 1560) ? (kb[i] + rb[i]) : 0.0f;
}

// merged small prep: [0,180) rwpack+Sv+bar, [180,276) scale pack, [276,3156) conv_w pack,
// [3156,7956) out_w cvt, [7956,10457) embed cvt
__global__ __launch_bounds__(512) void k_prep_misc(const float* __restrict__ rw,
                                                   const float* __restrict__ kw,
                                                   const float* __restrict__ sw,
                                                   const float* __restrict__ sb,
                                                   const float* __restrict__ rw2,
                                                   const float* __restrict__ cw,
                                                   const float* __restrict__ ow,
                                                   const float* __restrict__ embed,
                                                   f16* __restrict__ RWp,
                                                   float* __restrict__ Sv,
                                                   int* __restrict__ bar,
                                                   f16* __restrict__ swp,
                                                   float* __restrict__ sbp,
                                                   f16* __restrict__ rwp2,
                                                   f16* __restrict__ Wc2,
                                                   f16* __restrict__ outw,
                                                   f16* __restrict__ Eh) {
  const int blk = blockIdx.x, tid = threadIdx.x;
  if (blk < 180) {
    int i = blk * 512 + tid;                 // 92160 chunks of 8 halfs
    if (i < 92160) {
      int p = i / 7680;
      int rem = i - p * 7680;
      int tau = rem / 768;
      int r2 = rem - tau * 768;
      int f = r2 >> 6;
      int l = r2 & 63;
      int lc = tau * 16 + (l & 15);
      int n;
      if (lc < 24) n = lc;
      else if (lc < 32) n = -1;
      else { int run = (lc - 32) >> 5; n = 24 + (run * 12 + p) * 32 + ((lc - 32) & 31); }
      int k = f * 32 + ((l >> 4) << 3);
      f16x8 o;
      if (n >= 0) {
        const float* s = rw + (long)n * 385 + k;
#pragma unroll
        for (int e = 0; e < 8; ++e) o[e] = (f16)s[e];
      } else {
#pragma unroll
        for (int e = 0; e < 8; ++e) o[e] = (f16)0.0f;
      }
      *(f16x8*)(RWp + (long)i * 8) = o;
    }
    if (i < 1664)
      Sv[i] = (i < 1560) ? (rw[(long)i * 385 + 384] + kw[(long)i * 4097 + 4096]) : 0.0f;
    if (i < 8192) bar[i] = 0;
  } else if (blk < 276) {
    int i = (blk - 180) * 512 + tid;         // 49152
    if (i < 128 * 384) {
      int o = i / 384, k = i - o * 384;
      swp[i] = (f16)((o < 64) ? sw[o * 384 + k] : 0.0f);
      int o2 = i >> 7, k2 = i & 127;
      rwp2[i] = (f16)((k2 < 64) ? rw2[o2 * 64 + k2] : 0.0f);
    }
    if (i < 128) sbp[i] = (i < 64) ? sb[i] : 0.0f;
  } else if (blk < 3156) {
    int i = (blk - 276) * 512 + tid;         // 384*3840 = 1474560
    if (i < 384 * 3840) {
      int o = i / 3840;
      int c = i - o * 3840;
      int j = c / 384;
      int h = c - j * 384;
      Wc2[i] = (f16)cw[((long)o * 384 + h) * 10 + j];
    }
  } else if (blk < 7956) {
    long i = (long)(blk - 3156) * 512 + tid; // 2457600
    if (i < 128L * KO) outw[i] = (f16)ow[i];
  } else {
    long i = (long)(blk - 7956) * 512 + tid; // 1280128
    if (i < 10001L * 128) Eh[i] = (f16)embed[i];
  }
}

// XKh = f16( gather(embed_h, ids) @ Wk^T + biasc ) — gather fused into A-staging.
__global__ __launch_bounds__(256) void k_gemm_emb(const int* __restrict__ ids,  // (12800,32)
                                                  const f16* __restrict__ Eh,  // (10001,128)
                                                  const f16* __restrict__ W,   // (1664,4096)
                                                  f16* __restrict__ C,         // (12800,GP)
                                                  const float* __restrict__ bias) {
  __shared__ __align__(16) f16 As[128 * 32];
  __shared__ __align__(16) f16 Bs[128 * 32];
  __shared__ int idsl[128 * 32];               // 16 KB: ids for this block's 128 A-rows
  const int tid = threadIdx.x;
  const long rowA0 = (long)blockIdx.x * 128;
  const long rowB0 = (long)blockIdx.y * 128;
  const int w = tid >> 6, lane = tid & 63;
  const int q = lane >> 4, r16 = lane & 15;
  const int wr = w >> 1, wc = w & 1;
  f32x4 acc[4][4] = {};
  for (int i = tid; i < 4096; i += 256) idsl[i] = ids[rowA0 * 32 + i];
  const int srow = tid >> 2;
  const int scol = (tid & 3) * 8;
  const f16* gB0 = W + (rowB0 + srow) * 4096L + scol;
  const f16* gB1 = gB0 + 64L * 4096;
  f16* lA = As + tid * 8;
  f16* lB = Bs + tid * 8;
  for (int k0 = 0; k0 < 4096; k0 += 32) {
    __syncthreads();
    const int n = k0 >> 7;
    const int d = (k0 & 127) + scol;
    gld16(Eh + (size_t)idsl[srow * 32 + n] * 128 + d, lA);
    gld16(Eh + (size_t)idsl[(srow + 64) * 32 + n] * 128 + d, lA + 2048);
    gld16(gB0 + k0, lB);
    gld16(gB1 + k0, lB + 2048);
    __syncthreads();
    f16x8 af[4], bfr[4];
#pragma unroll
    for (int i = 0; i < 4; i++) {
      af[i]  = *(const f16x8*)&As[(wr * 64 + i * 16 + r16) * 32 + q * 8];
      bfr[i] = *(const f16x8*)&Bs[(wc * 64 + i * 16 + r16) * 32 + q * 8];
    }
#pragma unroll
    for (int i = 0; i < 4; i++)
#pragma unroll
      for (int j = 0; j < 4; j++)
        acc[i][j] = __builtin_amdgcn_mfma_f32_16x16x32_f16(af[i], bfr[j], acc[i][j], 0, 0, 0);
  }
#pragma unroll
  for (int i = 0; i < 4; i++)
#pragma unroll
    for (int j = 0; j < 4; j++) {
      long row = rowA0 + wr * 64 + i * 16 + q * 4;
      long col = rowB0 + wc * 64 + j * 16 + r16;
      float bv = bias[col];
#pragma unroll
      for (int r = 0; r < 4; r++)
        C[(row + r) * (long)GP + col] = (f16)(acc[i][j][r] + bv);
    }
}

// C = A(M x K) * W(N x K)^T (+bias[col]); m97-style global_load_lds staging.
// grid.z splits K (kLen MUST be a multiple of 32; partials at z*M*N).
// act: 0=f32, 1=f16, 2=relu->f16, 3=sigmoid->f32.
__global__ __launch_bounds__(256) void k_gemm_bt(const f16* __restrict__ A,
                                                 const f16* __restrict__ W,
                                                 void* __restrict__ Cv,
                                                 const float* __restrict__ bias,
                                                 int N, int K, int kLen, int act) {
  __shared__ __align__(16) f16 As[128 * 32];
  __shared__ __align__(16) f16 Bs[128 * 32];
  const int tid = threadIdx.x;
  const long rowA0 = (long)blockIdx.x * 128;
  const long rowB0 = (long)blockIdx.y * 128;
  const long ks = (long)blockIdx.z * kLen;
  const long zoff = (long)blockIdx.z * ((long)gridDim.x * 128 * N);
  const int w = tid >> 6, lane = tid & 63;
  const int q = lane >> 4, r16 = lane & 15;
  const int wr = w >> 1, wc = w & 1;
  f32x4 acc[4][4] = {};
  const int srow = tid >> 2;
  const int scol = (tid & 3) * 8;
  const f16* gA0 = A + (rowA0 + srow) * (long)K + ks + scol;
  const f16* gA1 = gA0 + 64L * K;
  const f16* gB0 = W + (rowB0 + srow) * (long)K + ks + scol;
  const f16* gB1 = gB0 + 64L * K;
  f16* lA = As + tid * 8;
  f16* lB = Bs + tid * 8;
  for (int k0 = 0; k0 < kLen; k0 += 32) {
    __syncthreads();
    gld16(gA0 + k0, lA);
    gld16(gA1 + k0, lA + 2048);
    gld16(gB0 + k0, lB);
    gld16(gB1 + k0, lB + 2048);
    __syncthreads();
    f16x8 af[4], bfr[4];
#pragma unroll
    for (int i = 0; i < 4; i++) {
      af[i]  = *(const f16x8*)&As[(wr * 64 + i * 16 + r16) * 32 + q * 8];
      bfr[i] = *(const f16x8*)&Bs[(wc * 64 + i * 16 + r16) * 32 + q * 8];
    }
#pragma unroll
    for (int i = 0; i < 4; i++)
#pragma unroll
      for (int j = 0; j < 4; j++)
        acc[i][j] = __builtin_amdgcn_mfma_f32_16x16x32_f16(af[i], bfr[j], acc[i][j], 0, 0, 0);
  }
#pragma unroll
  for (int i = 0; i < 4; i++)
#pragma unroll
    for (int j = 0; j < 4; j++) {
      long row = rowA0 + wr * 64 + i * 16 + q * 4;
      long col = rowB0 + wc * 64 + j * 16 + r16;
      float bv = bias ? bias[col] : 0.0f;
#pragma unroll
      for (int r = 0; r < 4; r++) {
        float v = acc[i][j][r] + bv;
        long off = (row + r) * (long)N + col + zoff;
        if (act == 0)      ((float*)Cv)[off] = v;
        else if (act == 1) ((f16*)Cv)[off]   = (f16)v;
        else if (act == 2) ((f16*)Cv)[off]   = (f16)fmaxf(v, 0.0f);
        else               ((float*)Cv)[off] = sigm(v);
      }
    }
}

// gate-partitioned weights-stationary recurrence v3: 192 blocks = 16 groups x 12
// members, 640 threads. h stores bypass L2 (sc0 sc1 -> LLC); h addresses are fresh
// each step so plain loads are coherent with NO acquire. Barrier = per-member flag
// (release store, own line) + wave-0 lanes polling all 12 flags RELAXED. No RMW,
// no acquire-invalidate -> XCD L2 (XKh/timep) survives across steps.
__global__ __launch_bounds__(640)
void k_recur_coop(const f16* __restrict__ XKh,    // (12800,1664) f16, bias folded
                  const f16* __restrict__ RWp,    // member-packed (12,10,12,64,8) f16
                  const float* __restrict__ Sv,   // (1664)
                  const float* __restrict__ timep,// (256,50)
                  f16* __restrict__ zbuf,         // (256,384) zeroed here
                  f16* __restrict__ hall,         // (50,256,384) f16
                  float* __restrict__ dists,      // (50,256)
                  int* __restrict__ bar) {
  extern __shared__ char smem[];
  f16*   Wl  = (f16*)smem;                        // 10 tiles x 6144 halfs
  float* xol = (float*)(smem + 122880);           // 16 x XOLS
  const int tid = threadIdx.x;
  const int g = blockIdx.x / NMEM;
  const int m = blockIdx.x - g * NMEM;
  const int b0 = g * 16;
  int* gflags = bar + g * 256;                    // 12 flags, stride 16 ints (64 B)
  int* ibar   = bar + 4096 + g * 32;              // init barrier state
  const int w = tid >> 6, lane = tid & 63;
  const int q = lane >> 4, r16 = lane & 15;
  {
    const f16* src = RWp + (size_t)m * 61440;
    for (int i = tid; i < 7680; i += 640)
      *(f16x8*)(Wl + (size_t)i * 8) = *(const f16x8*)(src + (size_t)i * 8);
  }
  int ncol = -1; float Svc = 0.0f;
  if (w < 10) {
    const int lc = w * 16 + r16;
    if (lc < 24) ncol = lc;
    else if (lc >= 32) { int run = (lc - 32) >> 5; ncol = 24 + (run * 12 + m) * 32 + ((lc - 32) & 31); }
    if (ncol >= 0) Svc = Sv[ncol];
  }
  {
    f16x8 z = {};
    for (int i = m * 640 + tid; i < 768; i += NMEM * 640)
      *(f16x8*)(zbuf + (size_t)b0 * 384 + (size_t)i * 8) = z;
  }
  gbar(ibar, NMEM);   // once: publish zbuf + Wl ready

  const int ch = tid & 31, bloc = tid >> 5;
  float creg = 0.0f;
  f16 xkc[4] = {};
  if (w < 10 && ncol >= 0) {
#pragma unroll
    for (int r = 0; r < 4; ++r)
      xkc[r] = XKh[((long)(b0 + q * 4 + r) * 50) * GP + ncol];
  }

  for (int t = 0; t < 50; ++t) {
    const f16* hprev = (t == 0) ? zbuf : (hall + (size_t)(t - 1) * 98304);
    f16 xkn[4] = {};
    if (w < 10) {
      // h loads first — the LLC-latency critical path
      f16x8 af[12];
      const f16* ab = hprev + (size_t)(b0 + r16) * 384 + q * 8;
#pragma unroll
      for (int f = 0; f < 12; ++f) af[f] = *(const f16x8*)(ab + f * 32);
      if (t < 49 && ncol >= 0) {
#pragma unroll
        for (int r = 0; r < 4; ++r)
          xkn[r] = XKh[((long)(b0 + q * 4 + r) * 50 + (t + 1)) * GP + ncol];
      }
      float tv4[4];
#pragma unroll
      for (int r = 0; r < 4; ++r) tv4[r] = timep[(b0 + q * 4 + r) * 50 + t];
      const f16* bp = Wl + (size_t)w * 6144 + lane * 8;
      f32x4 a0 = {};
#pragma unroll
      for (int f = 0; f < 12; ++f)
        a0 = __builtin_amdgcn_mfma_f32_16x16x32_f16(af[f], *(const f16x8*)(bp + f * 512), a0, 0, 0, 0);
      const int lc = w * 16 + r16;
#pragma unroll
      for (int r = 0; r < 4; ++r)
        xol[(q * 4 + r) * XOLS + lc] = a0[r] + (float)xkc[r] + tv4[r] * Svc;
    }
    __syncthreads();   // xol ready
    if (bloc < 16) {
      const int gb = b0 + bloc;
      const float* xr = xol + bloc * XOLS;
      float e1[12], e2[12], mx1 = -1e30f, mx2 = -1e30f;
#pragma unroll
      for (int l = 0; l < 12; ++l) {
        e1[l] = xr[l];      mx1 = fmaxf(mx1, e1[l]);
        e2[l] = xr[12 + l]; mx2 = fmaxf(mx2, e2[l]);
      }
      float s1 = 0.0f, s2 = 0.0f;
#pragma unroll
      for (int l = 0; l < 12; ++l) {
        e1[l] = __expf(e1[l] - mx1); s1 += e1[l];
        e2[l] = __expf(e2[l] - mx2); s2 += e2[l];
      }
      float cum1 = 0.0f;
      for (int l = 0; l <= m; ++l) cum1 += e1[l];
      const float fmv = cum1 / s1;
      float cum2 = 0.0f;
      for (int l = 11; l >= m; --l) cum2 += e2[l];
      const float imv = cum2 / s2;
      if (m == 0 && ch == 0) {
        float ds = 0.0f;
#pragma unroll
        for (int l = 0; l < 12; ++l) ds += (float)(12 - l) * e1[l];
        dists[t * 256 + gb] = 1.0f - ds / (12.0f * s1);
      }
      const float fv = sigm(xr[32 + ch]);
      const float iv = sigm(xr[64 + ch]);
      const float og = sigm(xr[96 + ch]);
      const float ci = tanhfast(xr[128 + ch]);
      const float ov = fmv * imv;
      const float cn = ov * (fv * creg + iv * ci) + (fmv - ov) * creg + (imv - ov) * ci;
      creg = cn;
      const float hv = og * tanhfast(cn);
      st_f16_llc(hall + ((size_t)t * 256 + gb) * 384 + m * 32 + ch, (f16)hv);
    }
    __syncthreads();   // drains h stores (vmcnt 0)
    if (tid == 0)
      __hip_atomic_store(gflags + m * 16, t + 1, __ATOMIC_RELEASE, __HIP_MEMORY_SCOPE_AGENT);
    if (w == 0 && lane < NMEM) {
      while (__hip_atomic_load(gflags + lane * 16, __ATOMIC_RELAXED, __HIP_MEMORY_SCOPE_AGENT) < t + 1)
        __builtin_amdgcn_s_sleep(2);
    }
    __syncthreads();
    asm volatile("" ::: "memory");
#pragma unroll
    for (int r = 0; r < 4; ++r) xkc[r] = xkn[r];
  }
}

// ld[b,t,:] = softmax_j(cumsum_j dist[t-9+j])
__global__ __launch_bounds__(256) void k_ld(const float* __restrict__ dists,
                                            float* __restrict__ ld) {
  int i = blockIdx.x * 256 + threadIdx.x;
  if (i >= 12800) return;
  int b = i / 50, t = i - b * 50;
  float v[10];
  float cum = 0.0f, mx = -1e30f;
#pragma unroll
  for (int j = 0; j < 10; j++) {
    int s = t - 9 + j;
    float d = (s >= 0) ? dists[s * 256 + b] : 0.0f;
    cum += d; v[j] = cum; mx = fmaxf(mx, cum);
  }
  float sum = 0.0f;
#pragma unroll
  for (int j = 0; j < 10; j++) { v[j] = __expf(v[j] - mx); sum += v[j]; }
  float inv = 1.0f / sum;
#pragma unroll
  for (int j = 0; j < 10; j++) ld[i * 10 + j] = v[j] * inv;
}

// lh_f16[(b,t)][j*384+h] = ld[b,t,j] * h_{t-9+j}[b,h]
__global__ __launch_bounds__(256) void k_lh(const float* __restrict__ ld,
                                            const f16* __restrict__ h_all,
                                            f16* __restrict__ lh) {
  int i = blockIdx.x * 256 + threadIdx.x;   // 12800*480
  int row = i / 480;
  int c = i - row * 480;
  int j = c / 48;
  int h0 = (c - j * 48) * 8;
  int b = row / 50, t = row - b * 50;
  int s = t - 9 + j;
  f16x8 o;
  if (s >= 0) {
    float wv = ld[row * 10 + j];
    f16x8 hv8 = *(const f16x8*)(h_all + ((size_t)s * 256 + b) * 384 + h0);
#pragma unroll
    for (int k = 0; k < 8; k++) o[k] = (f16)(wv * (float)hv8[k]);
  } else {
#pragma unroll
    for (int k = 0; k < 8; k++) o[k] = (f16)0.0f;
  }
  *(f16x8*)(lh + (long)row * KH + j * 384 + h0) = o;
}

// mlh_h[(b,t)][h] = mean_j
__global__ __launch_bounds__(256) void k_mlh(const float* __restrict__ ld,
                                             const f16* __restrict__ h_all,
                                             f16* __restrict__ mlh) {
  int i = blockIdx.x * 256 + threadIdx.x;   // 12800*384
  int row = i / 384, h = i - row * 384;
  int b = row / 50, t = row - b * 50;
  float acc = 0.0f;
#pragma unroll
  for (int j = 0; j < 10; j++) {
    int s = t - 9 + j;
    if (s >= 0) acc += ld[row * 10 + j] * (float)h_all[((size_t)s * 256 + b) * 384 + h];
  }
  mlh[i] = (f16)(acc * 0.1f);
}

// rnn_f16[b][t*384+h] = theme*(conv0+conv1+conv_b) + h
__global__ __launch_bounds__(256) void k_rnn(const float* __restrict__ theme,
                                             const float* __restrict__ convp,
                                             const float* __restrict__ cb,
                                             const f16* __restrict__ h_all,
                                             f16* __restrict__ rnn) {
  int i = blockIdx.x * 256 + threadIdx.x;   // 12800*384, ordered (b,t,h)
  int row = i / 384, h = i - row * 384;
  int b = row / 50, t = row - b * 50;
  float conv = convp[i] + convp[4915200 + i] + cb[h];
  float local = theme[i] * conv;
  float hv = (float)h_all[((size_t)t * 256 + b) * 384 + h];
  rnn[i] = (f16)(local + hv);
}

// out[i] = sum_z part[z][i] + out_b
__global__ __launch_bounds__(256) void k_red8(const float* __restrict__ part,
                                              const float* __restrict__ ob,
                                              float* __restrict__ out) {
  int i = blockIdx.x * 256 + threadIdx.x;   // 32768
  float s = 0.0f;
#pragma unroll
  for (int z = 0; z < 8; z++) s += part[z * 32768 + i];
  out[i] = s + ob[i & 127];
}

// ---------------- launch ----------------
extern "C" void kernel_launch(void* const* d_in, const int* in_sizes, int n_in,
                              void* d_out, int out_size, void* d_ws, size_t ws_size,
                              hipStream_t stream) {
  (void)in_sizes; (void)n_in; (void)out_size; (void)ws_size;
  const int*   node_ids  = (const int*)  d_in[0];
  const float* timep     = (const float*)d_in[3];
  const float* embed     = (const float*)d_in[6];
  const float* kernel_w  = (const float*)d_in[7];
  const float* kernel_b  = (const float*)d_in[8];
  const float* rec_w     = (const float*)d_in[9];
  const float* rec_b     = (const float*)d_in[10];
  const float* scale_w   = (const float*)d_in[11];
  const float* scale_b   = (const float*)d_in[12];
  const float* rescale_w = (const float*)d_in[13];
  const float* rescale_b = (const float*)d_in[14];
  const float* conv_w    = (const float*)d_in[15];
  const float* conv_b    = (const float*)d_in[16];
  const float* out_w     = (const float*)d_in[17];
  const float* out_b     = (const float*)d_in[18];

  char* ws = (char*)d_ws;
  f16*   lh      = (f16*)  (ws + OFF_LH);
  float* opart   = (float*)(ws + OFF_OPART);
  f16*   zbuf    = (f16*)  (ws + OFF_ZB);
  f16*   Wk      = (f16*)  (ws + OFF_WK);
  f16*   XKh     = (f16*)  (ws + OFF_XK);
  f16*   mlh_h   = (f16*)  (ws + OFF_MLH);
  f16*   s1h     = (f16*)  (ws + OFF_S1);
  float* theme   = (float*)(ws + OFF_TH);
  float* convbuf = (float*)(ws + OFF_CV);
  f16*   swp     = (f16*)  (ws + OFF_SWP);
  f16*   rwp2    = (f16*)  (ws + OFF_RWP2);
  float* sbp     = (float*)(ws + OFF_SBP);
  f16*   RWp     = (f16*)  (ws + OFF_RW);
  float* Sv      = (float*)(ws + OFF_SV);
  int*   bar     = (int*)  (ws + OFF_BAR);
  float* biasc   = (float*)(ws + OFF_BIASC);
  f16*   h_all   = (f16*)  (ws + OFF_HALL);
  float* ldbuf   = (float*)(ws + OFF_LD);
  f16*   Wc2     = (f16*)  (ws + OFF_WC2);
  f16*   rnn     = (f16*)  (ws + OFF_RNN);
  f16*   outw    = (f16*)  (ws + OFF_OUTW);
  f16*   Eh      = (f16*)  (ws + OFF_EH);

  float* outp  = (float*)d_out;          // (256,128)
  float* dists = outp + 256 * 128;       // (50,256)

  // phase 0: prep (2 kernels)
  k_prep_wk  <<<26624, 256, 0, stream>>>(kernel_w, kernel_b, rec_b, Wk, biasc);
  k_prep_misc<<<10457, 512, 0, stream>>>(rec_w, kernel_w, scale_w, scale_b, rescale_w,
                                         conv_w, out_w, embed,
                                         RWp, Sv, bar, swp, sbp, rwp2, Wc2, outw, Eh);
  // phase 1: XKh GEMM with fused embedding gather
  k_gemm_emb<<<dim3(100, 13), 256, 0, stream>>>(node_ids, Eh, Wk, XKh, biasc);
  // phase 2: recurrence (LLC-coherent h, flag barrier, no fences in loop)
  {
    hipFuncSetAttribute((const void*)k_recur_coop,
                        hipFuncAttributeMaxDynamicSharedMemorySize, RECUR_LDS);
    void* cargs[] = {(void*)&XKh, (void*)&RWp, (void*)&Sv, (void*)&timep,
                     (void*)&zbuf, (void*)&h_all, (void*)&dists, (void*)&bar};
    hipLaunchCooperativeKernel((void*)k_recur_coop, dim3(NBLK), dim3(640),
                               cargs, RECUR_LDS, stream);
  }
  // phase 3: deferred outputs
  k_ld  <<<50,    256, 0, stream>>>(dists, ldbuf);
  k_lh  <<<24000, 256, 0, stream>>>(ldbuf, h_all, lh);
  k_mlh <<<19200, 256, 0, stream>>>(ldbuf, h_all, mlh_h);
  k_gemm_bt<<<dim3(100, 1), 256, 0, stream>>>(mlh_h, swp, s1h, sbp, 128, 384, 384, 2);
  k_gemm_bt<<<dim3(100, 3), 256, 0, stream>>>(s1h, rwp2, theme, rescale_b, 384, 128, 128, 3);
  k_gemm_bt<<<dim3(100, 3, 2), 256, 0, stream>>>(lh, Wc2, convbuf, nullptr, 384, KH, KH / 2, 0);
  k_rnn <<<19200, 256, 0, stream>>>(theme, convbuf, conv_b, h_all, rnn);
  // phase 4: out = rnn @ out_w^T + out_b   (K split 8 ways: 2400 = 75*32, exact)
  k_gemm_bt<<<dim3(2, 1, 8), 256, 0, stream>>>(rnn, outw, opart, nullptr, 128, KO, KO / 8, 0);
  k_red8<<<128, 256, 0, stream>>>(opart, out_b, outp);
}

// Round 13
// 1029.876 us; speedup vs baseline: 1.2734x; 1.0857x over previous
//
#include <hip/hip_runtime.h>
#include <math.h>

// ---------------- types ----------------
typedef _Float16 f16;
typedef _Float16 f16x8 __attribute__((ext_vector_type(8)));
typedef float f32x4 __attribute__((ext_vector_type(4)));

#define DEV static __device__ __forceinline__

DEV float sigm(float x)  { return 1.0f / (1.0f + __expf(-x)); }
DEV float tanhfast(float x) { return 2.0f / (1.0f + __expf(-2.0f * x)) - 1.0f; }

// async global->LDS, 16B per lane (dest must be wave-uniform base + lane*16)
DEV void gld16(const void* g, void* l) {
  __builtin_amdgcn_global_load_lds((const __attribute__((address_space(1))) void*)g,
                                   (__attribute__((address_space(3))) void*)l, 16, 0, 0);
}

// LLC-coherent f16 store: sc0 sc1 bypasses L1/L2 so the value is visible
// device-wide without any wbl2/inv fence on the consumer side.
DEV void st_f16_llc(f16* p, f16 v) {
  unsigned int u = *(unsigned short*)&v;
  asm volatile("global_store_short %0, %1, off sc0 sc1" :: "v"(p), "v"(u) : "memory");
}

// init-only barrier (release/acquire) — used once before the t-loop
DEV void gbar(int* bar, int nblk) {
  __syncthreads();
  if (threadIdx.x == 0) {
    int* cnt = bar;
    int* gen = bar + 16;
    int g = __hip_atomic_load(gen, __ATOMIC_RELAXED, __HIP_MEMORY_SCOPE_AGENT);
    int a = __hip_atomic_fetch_add(cnt, 1, __ATOMIC_RELEASE, __HIP_MEMORY_SCOPE_AGENT);
    if (a == nblk - 1) {
      __hip_atomic_store(cnt, 0, __ATOMIC_RELAXED, __HIP_MEMORY_SCOPE_AGENT);
      __hip_atomic_store(gen, g + 1, __ATOMIC_RELEASE, __HIP_MEMORY_SCOPE_AGENT);
    } else {
      while (__hip_atomic_load(gen, __ATOMIC_RELAXED, __HIP_MEMORY_SCOPE_AGENT) == g)
        __builtin_amdgcn_s_sleep(1);
    }
    (void)__hip_atomic_load(gen, __ATOMIC_ACQUIRE, __HIP_MEMORY_SCOPE_AGENT);
  }
  __syncthreads();
}

// ---------------- problem constants ----------------
// B=256 V=50 N=32 D=128 H=384 L=12 CS=10 ND=4096 G=1560 OUT=128
#define GP 1664   // padded G (13*128) — XK gemm N and XKh row stride
#define KH 3840   // H*CS (conv gemm K)
#define KO 19200  // V*H  (out gemm K)
#define NGRP 16
#define NMEM 12
#define NBLK 192
#define XOLS 164  // xo local (LDS) row stride in f32
#define RECUR_LDS (122880 + 10496)   // Wl 10 tiles + xol 16x164 f32

// ---------------- workspace layout (bytes) ----------------
static constexpr size_t OFF_OPART = 0;                       // out partials 8*32768*4
static constexpr size_t OFF_ZB    = 104857600 - 262144;      // zbuf f16 196608
static constexpr size_t OFF_WK    = 104857600;               // 13631488
static constexpr size_t OFF_XK    = OFF_WK + 13631488;       // XKh f16 42598400
// aliases of the XK region (XKh dead after k_recur):
static constexpr size_t OFF_MLH   = OFF_XK;                  // mlh_h f16 9830400
static constexpr size_t OFF_S1    = OFF_XK + 9830400;        // s1h f16 3276800
static constexpr size_t OFF_TH    = OFF_XK + 13107200;       // theme f32 19660800
static constexpr size_t OFF_CV    = OFF_XK + 32768000;       // conv partials 2x19660800 (ends +72089600)
static constexpr size_t OFF_SWP   = OFF_XK + 72089600;       // swp f16 98304 (> XKh end)
static constexpr size_t OFF_RWP2  = OFF_XK + 72187904;       // rwp2 f16 98304
static constexpr size_t OFF_SBP   = OFF_XK + 72286208;       // sbp f32 512
static constexpr size_t OFF_RW    = OFF_XK + 85196800;       // RWpack f16 1474560
static constexpr size_t OFF_SV    = OFF_RW + 1474560;        // Sv f32 6656 (pad 8192)
static constexpr size_t OFF_BAR   = OFF_SV + 8192;           // flags + init bar (32 KB)
static constexpr size_t OFF_BIASC = OFF_BAR + 32768;         // 8192
static constexpr size_t OFF_HALL  = OFF_BIASC + 8192;        // h_all f16 9830400
static constexpr size_t OFF_LD    = OFF_HALL + 9830400;      // 512000
static constexpr size_t OFF_WC2   = OFF_LD + 512000;         // 2949120
static constexpr size_t OFF_RNN   = OFF_WC2 + 2949120;       // 9830400
static constexpr size_t OFF_OUTW  = OFF_RNN + 9830400;       // 4915200
static constexpr size_t OFF_EH    = OFF_OUTW + 4915200;      // embed f16 2560256

// ---------------- kernels ----------------

// kernel_w (1560 x 4097) -> Wk_f16 (1664 x 4096, zero-padded rows); biasc = kb+rb (padded 1664)
__global__ __launch_bounds__(256) void k_prep_wk(const float* __restrict__ kw,
                                                 const float* __restrict__ kb,
                                                 const float* __restrict__ rb,
                                                 f16* __restrict__ Wk,
                                                 float* __restrict__ biasc) {
  long i = (long)blockIdx.x * 256 + threadIdx.x;
  if (i < 1664L * 4096) {
    int nn = (int)(i >> 12);
    int k  = (int)(i & 4095);
    float v = (nn < 1560) ? kw[(long)nn * 4097 + k] : 0.0f;
    Wk[i] = (f16)v;
  }
  if (i < 1664) biasc[i] = (i < 1560) ? (kb[i] + rb[i]) : 0.0f;
}

// merged small prep: [0,180) rwpack+Sv+bar, [180,276) scale pack, [276,3156) conv_w pack,
// [3156,7956) out_w cvt, [7956,10457) embed cvt
__global__ __launch_bounds__(512) void k_prep_misc(const float* __restrict__ rw,
                                                   const float* __restrict__ kw,
                                                   const float* __restrict__ sw,
                                                   const float* __restrict__ sb,
                                                   const float* __restrict__ rw2,
                                                   const float* __restrict__ cw,
                                                   const float* __restrict__ ow,
                                                   const float* __restrict__ embed,
                                                   f16* __restrict__ RWp,
                                                   float* __restrict__ Sv,
                                                   int* __restrict__ bar,
                                                   f16* __restrict__ swp,
                                                   float* __restrict__ sbp,
                                                   f16* __restrict__ rwp2,
                                                   f16* __restrict__ Wc2,
                                                   f16* __restrict__ outw,
                                                   f16* __restrict__ Eh) {
  const int blk = blockIdx.x, tid = threadIdx.x;
  if (blk < 180) {
    int i = blk * 512 + tid;                 // 92160 chunks of 8 halfs
    if (i < 92160) {
      int p = i / 7680;
      int rem = i - p * 7680;
      int tau = rem / 768;
      int r2 = rem - tau * 768;
      int f = r2 >> 6;
      int l = r2 & 63;
      int lc = tau * 16 + (l & 15);
      int n;
      if (lc < 24) n = lc;
      else if (lc < 32) n = -1;
      else { int run = (lc - 32) >> 5; n = 24 + (run * 12 + p) * 32 + ((lc - 32) & 31); }
      int k = f * 32 + ((l >> 4) << 3);
      f16x8 o;
      if (n >= 0) {
        const float* s = rw + (long)n * 385 + k;
#pragma unroll
        for (int e = 0; e < 8; ++e) o[e] = (f16)s[e];
      } else {
#pragma unroll
        for (int e = 0; e < 8; ++e) o[e] = (f16)0.0f;
      }
      *(f16x8*)(RWp + (long)i * 8) = o;
    }
    if (i < 1664)
      Sv[i] = (i < 1560) ? (rw[(long)i * 385 + 384] + kw[(long)i * 4097 + 4096]) : 0.0f;
    if (i < 8192) bar[i] = 0;
  } else if (blk < 276) {
    int i = (blk - 180) * 512 + tid;         // 49152
    if (i < 128 * 384) {
      int o = i / 384, k = i - o * 384;
      swp[i] = (f16)((o < 64) ? sw[o * 384 + k] : 0.0f);
      int o2 = i >> 7, k2 = i & 127;
      rwp2[i] = (f16)((k2 < 64) ? rw2[o2 * 64 + k2] : 0.0f);
    }
    if (i < 128) sbp[i] = (i < 64) ? sb[i] : 0.0f;
  } else if (blk < 3156) {
    int i = (blk - 276) * 512 + tid;         // 384*3840 = 1474560
    if (i < 384 * 3840) {
      int o = i / 3840;
      int c = i - o * 3840;
      int j = c / 384;
      int h = c - j * 384;
      Wc2[i] = (f16)cw[((long)o * 384 + h) * 10 + j];
    }
  } else if (blk < 7956) {
    long i = (long)(blk - 3156) * 512 + tid; // 2457600
    if (i < 128L * KO) outw[i] = (f16)ow[i];
  } else {
    long i = (long)(blk - 7956) * 512 + tid; // 1280128
    if (i < 10001L * 128) Eh[i] = (f16)embed[i];
  }
}

// XKh = f16( gather(embed_h, ids) @ Wk^T + biasc ).
// v2: ids kept in registers, next n-group's ids prefetched 4 k-iters ahead —
// staging address calc is pure VALU (no LDS dependency on the critical path).
__global__ __launch_bounds__(256) void k_gemm_emb(const int* __restrict__ ids,  // (12800,32)
                                                  const f16* __restrict__ Eh,  // (10001,128)
                                                  const f16* __restrict__ W,   // (1664,4096)
                                                  f16* __restrict__ C,         // (12800,GP)
                                                  const float* __restrict__ bias) {
  __shared__ __align__(16) f16 As[128 * 32];
  __shared__ __align__(16) f16 Bs[128 * 32];
  const int tid = threadIdx.x;
  const long rowA0 = (long)blockIdx.x * 128;
  const long rowB0 = (long)blockIdx.y * 128;
  const int w = tid >> 6, lane = tid & 63;
  const int q = lane >> 4, r16 = lane & 15;
  const int wr = w >> 1, wc = w & 1;
  f32x4 acc[4][4] = {};
  const int srow = tid >> 2;
  const int scol = (tid & 3) * 8;
  const int* idr0 = ids + (rowA0 + srow) * 32;
  const int* idr1 = ids + (rowA0 + srow + 64) * 32;
  const f16* gB0 = W + (rowB0 + srow) * 4096L + scol;
  const f16* gB1 = gB0 + 64L * 4096;
  f16* lA = As + tid * 8;
  f16* lB = Bs + tid * 8;
  int cur0 = idr0[0], cur1 = idr1[0];
  for (int n = 0; n < 32; ++n) {
    // prefetch next group's ids — 4 k-iterations of slack before use
    int nx0 = 0, nx1 = 0;
    if (n < 31) { nx0 = idr0[n + 1]; nx1 = idr1[n + 1]; }
#pragma unroll
    for (int kk = 0; kk < 4; ++kk) {
      const int k0 = n * 128 + kk * 32;
      const int d = kk * 32 + scol;
      __syncthreads();
      gld16(Eh + (size_t)cur0 * 128 + d, lA);
      gld16(Eh + (size_t)cur1 * 128 + d, lA + 2048);
      gld16(gB0 + k0, lB);
      gld16(gB1 + k0, lB + 2048);
      __syncthreads();
      f16x8 af[4], bfr[4];
#pragma unroll
      for (int i = 0; i < 4; i++) {
        af[i]  = *(const f16x8*)&As[(wr * 64 + i * 16 + r16) * 32 + q * 8];
        bfr[i] = *(const f16x8*)&Bs[(wc * 64 + i * 16 + r16) * 32 + q * 8];
      }
#pragma unroll
      for (int i = 0; i < 4; i++)
#pragma unroll
        for (int j = 0; j < 4; j++)
          acc[i][j] = __builtin_amdgcn_mfma_f32_16x16x32_f16(af[i], bfr[j], acc[i][j], 0, 0, 0);
    }
    cur0 = nx0; cur1 = nx1;
  }
#pragma unroll
  for (int i = 0; i < 4; i++)
#pragma unroll
    for (int j = 0; j < 4; j++) {
      long row = rowA0 + wr * 64 + i * 16 + q * 4;
      long col = rowB0 + wc * 64 + j * 16 + r16;
      float bv = bias[col];
#pragma unroll
      for (int r = 0; r < 4; r++)
        C[(row + r) * (long)GP + col] = (f16)(acc[i][j][r] + bv);
    }
}

// conv GEMM with lh fused into A-staging: A[row][j*384+h] = ld[row][j]*h_all[t-9+j][b][h]
// (j is uniform per 32-wide k-window since 384 = 12*32). C = f32 partials (grid.z=2).
__global__ __launch_bounds__(256) void k_gemm_conv(const float* __restrict__ ld,   // (12800,10)
                                                   const f16* __restrict__ h_all, // (50,256,384)
                                                   const f16* __restrict__ W,     // Wc2 (384,3840)
                                                   float* __restrict__ C) {
  __shared__ __align__(16) f16 As[128 * 32];
  __shared__ __align__(16) f16 Bs[128 * 32];
  const int tid = threadIdx.x;
  const long rowA0 = (long)blockIdx.x * 128;
  const long rowB0 = (long)blockIdx.y * 128;
  const int ks = blockIdx.z * 1920;
  const long zoff = (long)blockIdx.z * (12800L * 384);
  const int w = tid >> 6, lane = tid & 63;
  const int q = lane >> 4, r16 = lane & 15;
  const int wr = w >> 1, wc = w & 1;
  f32x4 acc[4][4] = {};
  const int srow = tid >> 2;
  const int scol = (tid & 3) * 8;
  const int row0 = (int)rowA0 + srow, row1 = row0 + 64;
  const int b0r = row0 / 50, t0r = row0 - b0r * 50;
  const int b1r = row1 / 50, t1r = row1 - b1r * 50;
  const f16* gB0 = W + (rowB0 + srow) * (long)KH + ks + scol;
  const f16* gB1 = gB0 + 64L * KH;
  f16* lB = Bs + tid * 8;
  for (int k0 = 0; k0 < 1920; k0 += 32) {
    const int col0 = ks + k0;
    const int j = col0 / 384;
    const int hh = col0 - j * 384 + scol;
    const int s0 = t0r - 9 + j, s1 = t1r - 9 + j;
    __syncthreads();
    gld16(gB0 + k0, lB);
    gld16(gB1 + k0, lB + 2048);
    f16x8 a0v = {}, a1v = {};
    if (s0 >= 0) {
      const float lv = ld[row0 * 10 + j];
      f16x8 hv = *(const f16x8*)(h_all + ((size_t)s0 * 256 + b0r) * 384 + hh);
#pragma unroll
      for (int e = 0; e < 8; ++e) a0v[e] = (f16)((float)hv[e] * lv);
    }
    if (s1 >= 0) {
      const float lv = ld[row1 * 10 + j];
      f16x8 hv = *(const f16x8*)(h_all + ((size_t)s1 * 256 + b1r) * 384 + hh);
#pragma unroll
      for (int e = 0; e < 8; ++e) a1v[e] = (f16)((float)hv[e] * lv);
    }
    *(f16x8*)&As[srow * 32 + scol] = a0v;
    *(f16x8*)&As[(srow + 64) * 32 + scol] = a1v;
    __syncthreads();
    f16x8 af[4], bfr[4];
#pragma unroll
    for (int i = 0; i < 4; i++) {
      af[i]  = *(const f16x8*)&As[(wr * 64 + i * 16 + r16) * 32 + q * 8];
      bfr[i] = *(const f16x8*)&Bs[(wc * 64 + i * 16 + r16) * 32 + q * 8];
    }
#pragma unroll
    for (int i = 0; i < 4; i++)
#pragma unroll
      for (int j2 = 0; j2 < 4; j2++)
        acc[i][j2] = __builtin_amdgcn_mfma_f32_16x16x32_f16(af[i], bfr[j2], acc[i][j2], 0, 0, 0);
  }
#pragma unroll
  for (int i = 0; i < 4; i++)
#pragma unroll
    for (int j2 = 0; j2 < 4; j2++) {
      long row = rowA0 + wr * 64 + i * 16 + q * 4;
      long col = rowB0 + wc * 64 + j2 * 16 + r16;
#pragma unroll
      for (int r = 0; r < 4; r++)
        C[(row + r) * 384L + col + zoff] = acc[i][j2][r];
    }
}

// C = A(M x K) * W(N x K)^T (+bias[col]); m97-style global_load_lds staging.
// grid.z splits K (kLen multiple of 32; partials at z*M*N). act: 0=f32, 1=f16, 2=relu->f16, 3=sigmoid->f32.
__global__ __launch_bounds__(256) void k_gemm_bt(const f16* __restrict__ A,
                                                 const f16* __restrict__ W,
                                                 void* __restrict__ Cv,
                                                 const float* __restrict__ bias,
                                                 int N, int K, int kLen, int act) {
  __shared__ __align__(16) f16 As[128 * 32];
  __shared__ __align__(16) f16 Bs[128 * 32];
  const int tid = threadIdx.x;
  const long rowA0 = (long)blockIdx.x * 128;
  const long rowB0 = (long)blockIdx.y * 128;
  const long ks = (long)blockIdx.z * kLen;
  const long zoff = (long)blockIdx.z * ((long)gridDim.x * 128 * N);
  const int w = tid >> 6, lane = tid & 63;
  const int q = lane >> 4, r16 = lane & 15;
  const int wr = w >> 1, wc = w & 1;
  f32x4 acc[4][4] = {};
  const int srow = tid >> 2;
  const int scol = (tid & 3) * 8;
  const f16* gA0 = A + (rowA0 + srow) * (long)K + ks + scol;
  const f16* gA1 = gA0 + 64L * K;
  const f16* gB0 = W + (rowB0 + srow) * (long)K + ks + scol;
  const f16* gB1 = gB0 + 64L * K;
  f16* lA = As + tid * 8;
  f16* lB = Bs + tid * 8;
  for (int k0 = 0; k0 < kLen; k0 += 32) {
    __syncthreads();
    gld16(gA0 + k0, lA);
    gld16(gA1 + k0, lA + 2048);
    gld16(gB0 + k0, lB);
    gld16(gB1 + k0, lB + 2048);
    __syncthreads();
    f16x8 af[4], bfr[4];
#pragma unroll
    for (int i = 0; i < 4; i++) {
      af[i]  = *(const f16x8*)&As[(wr * 64 + i * 16 + r16) * 32 + q * 8];
      bfr[i] = *(const f16x8*)&Bs[(wc * 64 + i * 16 + r16) * 32 + q * 8];
    }
#pragma unroll
    for (int i = 0; i < 4; i++)
#pragma unroll
      for (int j = 0; j < 4; j++)
        acc[i][j] = __builtin_amdgcn_mfma_f32_16x16x32_f16(af[i], bfr[j], acc[i][j], 0, 0, 0);
  }
#pragma unroll
  for (int i = 0; i < 4; i++)
#pragma unroll
    for (int j = 0; j < 4; j++) {
      long row = rowA0 + wr * 64 + i * 16 + q * 4;
      long col = rowB0 + wc * 64 + j * 16 + r16;
      float bv = bias ? bias[col] : 0.0f;
#pragma unroll
      for (int r = 0; r < 4; r++) {
        float v = acc[i][j][r] + bv;
        long off = (row + r) * (long)N + col + zoff;
        if (act == 0)      ((float*)Cv)[off] = v;
        else if (act == 1) ((f16*)Cv)[off]   = (f16)v;
        else if (act == 2) ((f16*)Cv)[off]   = (f16)fmaxf(v, 0.0f);
        else               ((float*)Cv)[off] = sigm(v);
      }
    }
}

// gate-partitioned weights-stationary recurrence v3 (R12-proven): 192 blocks =
// 16 groups x 12 members, 640 threads. LLC h stores, flag barrier, no fences.
__global__ __launch_bounds__(640)
void k_recur_coop(const f16* __restrict__ XKh,
                  const f16* __restrict__ RWp,
                  const float* __restrict__ Sv,
                  const float* __restrict__ timep,
                  f16* __restrict__ zbuf,
                  f16* __restrict__ hall,
                  float* __restrict__ dists,
                  int* __restrict__ bar) {
  extern __shared__ char smem[];
  f16*   Wl  = (f16*)smem;
  float* xol = (float*)(smem + 122880);
  const int tid = threadIdx.x;
  const int g = blockIdx.x / NMEM;
  const int m = blockIdx.x - g * NMEM;
  const int b0 = g * 16;
  int* gflags = bar + g * 256;
  int* ibar   = bar + 4096 + g * 32;
  const int w = tid >> 6, lane = tid & 63;
  const int q = lane >> 4, r16 = lane & 15;
  {
    const f16* src = RWp + (size_t)m * 61440;
    for (int i = tid; i < 7680; i += 640)
      *(f16x8*)(Wl + (size_t)i * 8) = *(const f16x8*)(src + (size_t)i * 8);
  }
  int ncol = -1; float Svc = 0.0f;
  if (w < 10) {
    const int lc = w * 16 + r16;
    if (lc < 24) ncol = lc;
    else if (lc >= 32) { int run = (lc - 32) >> 5; ncol = 24 + (run * 12 + m) * 32 + ((lc - 32) & 31); }
    if (ncol >= 0) Svc = Sv[ncol];
  }
  {
    f16x8 z = {};
    for (int i = m * 640 + tid; i < 768; i += NMEM * 640)
      *(f16x8*)(zbuf + (size_t)b0 * 384 + (size_t)i * 8) = z;
  }
  gbar(ibar, NMEM);

  const int ch = tid & 31, bloc = tid >> 5;
  float creg = 0.0f;
  f16 xkc[4] = {};
  if (w < 10 && ncol >= 0) {
#pragma unroll
    for (int r = 0; r < 4; ++r)
      xkc[r] = XKh[((long)(b0 + q * 4 + r) * 50) * GP + ncol];
  }

  for (int t = 0; t < 50; ++t) {
    const f16* hprev = (t == 0) ? zbuf : (hall + (size_t)(t - 1) * 98304);
    f16 xkn[4] = {};
    if (w < 10) {
      f16x8 af[12];
      const f16* ab = hprev + (size_t)(b0 + r16) * 384 + q * 8;
#pragma unroll
      for (int f = 0; f < 12; ++f) af[f] = *(const f16x8*)(ab + f * 32);
      if (t < 49 && ncol >= 0) {
#pragma unroll
        for (int r = 0; r < 4; ++r)
          xkn[r] = XKh[((long)(b0 + q * 4 + r) * 50 + (t + 1)) * GP + ncol];
      }
      float tv4[4];
#pragma unroll
      for (int r = 0; r < 4; ++r) tv4[r] = timep[(b0 + q * 4 + r) * 50 + t];
      const f16* bp = Wl + (size_t)w * 6144 + lane * 8;
      f32x4 a0 = {};
#pragma unroll
      for (int f = 0; f < 12; ++f)
        a0 = __builtin_amdgcn_mfma_f32_16x16x32_f16(af[f], *(const f16x8*)(bp + f * 512), a0, 0, 0, 0);
      const int lc = w * 16 + r16;
#pragma unroll
      for (int r = 0; r < 4; ++r)
        xol[(q * 4 + r) * XOLS + lc] = a0[r] + (float)xkc[r] + tv4[r] * Svc;
    }
    __syncthreads();
    if (bloc < 16) {
      const int gb = b0 + bloc;
      const float* xr = xol + bloc * XOLS;
      float e1[12], e2[12], mx1 = -1e30f, mx2 = -1e30f;
#pragma unroll
      for (int l = 0; l < 12; ++l) {
        e1[l] = xr[l];      mx1 = fmaxf(mx1, e1[l]);
        e2[l] = xr[12 + l]; mx2 = fmaxf(mx2, e2[l]);
      }
      float s1 = 0.0f, s2 = 0.0f;
#pragma unroll
      for (int l = 0; l < 12; ++l) {
        e1[l] = __expf(e1[l] - mx1); s1 += e1[l];
        e2[l] = __expf(e2[l] - mx2); s2 += e2[l];
      }
      float cum1 = 0.0f;
      for (int l = 0; l <= m; ++l) cum1 += e1[l];
      const float fmv = cum1 / s1;
      float cum2 = 0.0f;
      for (int l = 11; l >= m; --l) cum2 += e2[l];
      const float imv = cum2 / s2;
      if (m == 0 && ch == 0) {
        float ds = 0.0f;
#pragma unroll
        for (int l = 0; l < 12; ++l) ds += (float)(12 - l) * e1[l];
        dists[t * 256 + gb] = 1.0f - ds / (12.0f * s1);
      }
      const float fv = sigm(xr[32 + ch]);
      const float iv = sigm(xr[64 + ch]);
      const float og = sigm(xr[96 + ch]);
      const float ci = tanhfast(xr[128 + ch]);
      const float ov = fmv * imv;
      const float cn = ov * (fv * creg + iv * ci) + (fmv - ov) * creg + (imv - ov) * ci;
      creg = cn;
      const float hv = og * tanhfast(cn);
      st_f16_llc(hall + ((size_t)t * 256 + gb) * 384 + m * 32 + ch, (f16)hv);
    }
    __syncthreads();
    if (tid == 0)
      __hip_atomic_store(gflags + m * 16, t + 1, __ATOMIC_RELEASE, __HIP_MEMORY_SCOPE_AGENT);
    if (w == 0 && lane < NMEM) {
      while (__hip_atomic_load(gflags + lane * 16, __ATOMIC_RELAXED, __HIP_MEMORY_SCOPE_AGENT) < t + 1)
        __builtin_amdgcn_s_sleep(2);
    }
    __syncthreads();
    asm volatile("" ::: "memory");
#pragma unroll
    for (int r = 0; r < 4; ++r) xkc[r] = xkn[r];
  }
}

// ld[b,t,:] = softmax_j(cumsum_j dist[t-9+j])
__global__ __launch_bounds__(256) void k_ld(const float* __restrict__ dists,
                                            float* __restrict__ ld) {
  int i = blockIdx.x * 256 + threadIdx.x;
  if (i >= 12800) return;
  int b = i / 50, t = i - b * 50;
  float v[10];
  float cum = 0.0f, mx = -1e30f;
#pragma unroll
  for (int j = 0; j < 10; j++) {
    int s = t - 9 + j;
    float d = (s >= 0) ? dists[s * 256 + b] : 0.0f;
    cum += d; v[j] = cum; mx = fmaxf(mx, cum);
  }
  float sum = 0.0f;
#pragma unroll
  for (int j = 0; j < 10; j++) { v[j] = __expf(v[j] - mx); sum += v[j]; }
  float inv = 1.0f / sum;
#pragma unroll
  for (int j = 0; j < 10; j++) ld[i * 10 + j] = v[j] * inv;
}

// mlh_h[(b,t)][h] = mean_j ld*h
__global__ __launch_bounds__(256) void k_mlh(const float* __restrict__ ld,
                                             const f16* __restrict__ h_all,
                                             f16* __restrict__ mlh) {
  int i = blockIdx.x * 256 + threadIdx.x;   // 12800*384
  int row = i / 384, h = i - row * 384;
  int b = row / 50, t = row - b * 50;
  float acc = 0.0f;
#pragma unroll
  for (int j = 0; j < 10; j++) {
    int s = t - 9 + j;
    if (s >= 0) acc += ld[row * 10 + j] * (float)h_all[((size_t)s * 256 + b) * 384 + h];
  }
  mlh[i] = (f16)(acc * 0.1f);
}

// rnn_f16[b][t*384+h] = theme*(conv0+conv1+conv_b) + h
__global__ __launch_bounds__(256) void k_rnn(const float* __restrict__ theme,
                                             const float* __restrict__ convp,
                                             const float* __restrict__ cb,
                                             const f16* __restrict__ h_all,
                                             f16* __restrict__ rnn) {
  int i = blockIdx.x * 256 + threadIdx.x;   // 12800*384, ordered (b,t,h)
  int row = i / 384, h = i - row * 384;
  int b = row / 50, t = row - b * 50;
  float conv = convp[i] + convp[4915200 + i] + cb[h];
  float local = theme[i] * conv;
  float hv = (float)h_all[((size_t)t * 256 + b) * 384 + h];
  rnn[i] = (f16)(local + hv);
}

// out[i] = sum_z part[z][i] + out_b
__global__ __launch_bounds__(256) void k_red8(const float* __restrict__ part,
                                              const float* __restrict__ ob,
                                              float* __restrict__ out) {
  int i = blockIdx.x * 256 + threadIdx.x;   // 32768
  float s = 0.0f;
#pragma unroll
  for (int z = 0; z < 8; z++) s += part[z * 32768 + i];
  out[i] = s + ob[i & 127];
}

// ---------------- launch ----------------
extern "C" void kernel_launch(void* const* d_in, const int* in_sizes, int n_in,
                              void* d_out, int out_size, void* d_ws, size_t ws_size,
                              hipStream_t stream) {
  (void)in_sizes; (void)n_in; (void)out_size; (void)ws_size;
  const int*   node_ids  = (const int*)  d_in[0];
  const float* timep     = (const float*)d_in[3];
  const float* embed     = (const float*)d_in[6];
  const float* kernel_w  = (const float*)d_in[7];
  const float* kernel_b  = (const float*)d_in[8];
  const float* rec_w     = (const float*)d_in[9];
  const float* rec_b     = (const float*)d_in[10];
  const float* scale_w   = (const float*)d_in[11];
  const float* scale_b   = (const float*)d_in[12];
  const float* rescale_w = (const float*)d_in[13];
  const float* rescale_b = (const float*)d_in[14];
  const float* conv_w    = (const float*)d_in[15];
  const float* conv_b    = (const float*)d_in[16];
  const float* out_w     = (const float*)d_in[17];
  const float* out_b     = (const float*)d_in[18];

  char* ws = (char*)d_ws;
  float* opart   = (float*)(ws + OFF_OPART);
  f16*   zbuf    = (f16*)  (ws + OFF_ZB);
  f16*   Wk      = (f16*)  (ws + OFF_WK);
  f16*   XKh     = (f16*)  (ws + OFF_XK);
  f16*   mlh_h   = (f16*)  (ws + OFF_MLH);
  f16*   s1h     = (f16*)  (ws + OFF_S1);
  float* theme   = (float*)(ws + OFF_TH);
  float* convbuf = (float*)(ws + OFF_CV);
  f16*   swp     = (f16*)  (ws + OFF_SWP);
  f16*   rwp2    = (f16*)  (ws + OFF_RWP2);
  float* sbp     = (float*)(ws + OFF_SBP);
  f16*   RWp     = (f16*)  (ws + OFF_RW);
  float* Sv      = (float*)(ws + OFF_SV);
  int*   bar     = (int*)  (ws + OFF_BAR);
  float* biasc   = (float*)(ws + OFF_BIASC);
  f16*   h_all   = (f16*)  (ws + OFF_HALL);
  float* ldbuf   = (float*)(ws + OFF_LD);
  f16*   Wc2     = (f16*)  (ws + OFF_WC2);
  f16*   rnn     = (f16*)  (ws + OFF_RNN);
  f16*   outw    = (f16*)  (ws + OFF_OUTW);
  f16*   Eh      = (f16*)  (ws + OFF_EH);

  float* outp  = (float*)d_out;          // (256,128)
  float* dists = outp + 256 * 128;       // (50,256)

  // phase 0: prep
  k_prep_wk  <<<26624, 256, 0, stream>>>(kernel_w, kernel_b, rec_b, Wk, biasc);
  k_prep_misc<<<10457, 512, 0, stream>>>(rec_w, kernel_w, scale_w, scale_b, rescale_w,
                                         conv_w, out_w, embed,
                                         RWp, Sv, bar, swp, sbp, rwp2, Wc2, outw, Eh);
  // phase 1: XKh GEMM with fused embedding gather (register-prefetched ids)
  k_gemm_emb<<<dim3(100, 13), 256, 0, stream>>>(node_ids, Eh, Wk, XKh, biasc);
  // phase 2: recurrence
  {
    hipFuncSetAttribute((const void*)k_recur_coop,
                        hipFuncAttributeMaxDynamicSharedMemorySize, RECUR_LDS);
    void* cargs[] = {(void*)&XKh, (void*)&RWp, (void*)&Sv, (void*)&timep,
                     (void*)&zbuf, (void*)&h_all, (void*)&dists, (void*)&bar};
    hipLaunchCooperativeKernel((void*)k_recur_coop, dim3(NBLK), dim3(640),
                               cargs, RECUR_LDS, stream);
  }
  // phase 3: deferred outputs (lh fused into conv GEMM staging)
  k_ld  <<<50,    256, 0, stream>>>(dists, ldbuf);
  k_mlh <<<19200, 256, 0, stream>>>(ldbuf, h_all, mlh_h);
  k_gemm_bt<<<dim3(100, 1), 256, 0, stream>>>(mlh_h, swp, s1h, sbp, 128, 384, 384, 2);
  k_gemm_bt<<<dim3(100, 3), 256, 0, stream>>>(s1h, rwp2, theme, rescale_b, 384, 128, 128, 3);
  k_gemm_conv<<<dim3(100, 3, 2), 256, 0, stream>>>(ldbuf, h_all, Wc2, convbuf);
  k_rnn <<<19200, 256, 0, stream>>>(theme, convbuf, conv_b, h_all, rnn);
  // phase 4: out = rnn @ out_w^T + out_b   (K split 8 ways: 2400 = 75*32, exact)
  k_gemm_bt<<<dim3(2, 1, 8), 256, 0, stream>>>(rnn, outw, opart, nullptr, 128, KO, KO / 8, 0);
  k_red8<<<128, 256, 0, stream>>>(opart, out_b, outp);
}